// Round 11
// baseline (176.555 us; speedup 1.0000x reference)
//
#include <hip/hip_runtime.h>
#include <stdint.h>

typedef __bf16 bf16;
typedef __attribute__((ext_vector_type(2))) __bf16 bf16x2;
typedef __attribute__((ext_vector_type(4))) __bf16 bf16x4;
typedef __attribute__((ext_vector_type(8))) __bf16 bf16x8;
typedef __attribute__((ext_vector_type(4))) float f32x4;
typedef __attribute__((ext_vector_type(16))) float f32x16;

#define LOG2E_OVER_8 0.18033688011112042f  // log2(e)/sqrt(64), folded into q

#if __has_builtin(__builtin_amdgcn_exp2f)
#define EXP2(x) __builtin_amdgcn_exp2f(x)   // raw v_exp_f32: D = 2^S0
#else
#define EXP2(x) exp2f(x)
#endif

// async global->LDS, 16B/lane; LDS dest = wave-uniform base + lane*16
__device__ __forceinline__ void gl_lds16(const bf16* g, bf16* l) {
  __builtin_amdgcn_global_load_lds(
      (const __attribute__((address_space(1))) void*)g,
      (__attribute__((address_space(3))) void*)l, 16, 0, 0);
}
// wait own loads, then sync -> everyone's loads are in LDS; DMA issued after
// this line stays in flight through the whole compute phase.
#define WAIT_VM0_BARRIER() asm volatile("s_waitcnt vmcnt(0)\n\ts_barrier" ::: "memory")

__device__ __forceinline__ uint32_t pack2(float a, float b) {
  union { bf16x2 v; uint32_t u; } z;
  z.v[0] = (bf16)a; z.v[1] = (bf16)b;
  return z.u;
}

// v_permlane32_swap_b32 a, b : a.hi31 <-> b.lo31
//   after: a = {a.lo, b.lo}, b = {a.hi, b.hi}
__device__ __forceinline__ void pl32swap(uint32_t& a, uint32_t& b) {
  asm("v_permlane32_swap_b32 %0, %1" : "+v"(a), "+v"(b));
}

// ---------------- fused fp32 -> bf16 convert (x, qkv_w, out_w) ----------------
#define N_X  (4096 * 1024)
#define N_WQ (3072 * 1024)
#define N_WO (1024 * 1024)
__global__ __launch_bounds__(256) void cvt3_kernel(const float* __restrict__ x,
                                                   const float* __restrict__ wq,
                                                   const float* __restrict__ wo,
                                                   bf16* __restrict__ d) {
  int i = (blockIdx.x * 256 + threadIdx.x) * 8;
  const float* s;
  if (i < N_X) s = x + i;
  else if (i < N_X + N_WQ) s = wq + (i - N_X);
  else s = wo + (i - N_X - N_WQ);
  float4 a = *(const float4*)s;
  float4 b = *(const float4*)(s + 4);
  bf16x8 o;
  o[0] = (bf16)a.x; o[1] = (bf16)a.y; o[2] = (bf16)a.z; o[3] = (bf16)a.w;
  o[4] = (bf16)b.x; o[5] = (bf16)b.y; o[6] = (bf16)b.z; o[7] = (bf16)b.w;
  *(bf16x8*)(d + i) = o;
}

// ---------------- NT GEMM, single-barrier prefetch + XCD supertiling ----------------
// EPI=0: 128x128 tile, BK=32, grid 768, scatter epilogue via LDS -> q,k,vT
// EPI=1: 64x128 tile, BK=64 (2 chunks/barrier, 16 barriers), grid 512,
//        fp32 out + bias. LDS 48KB -> still 3 blocks/CU.
// LDS layout: chunks of 32 cols: [kc][rows][32] (keeps proven bank pattern).
template <int EPI>
__global__ __launch_bounds__(256, 3) void gemm_bt(
    const bf16* __restrict__ A, const bf16* __restrict__ Bw,
    const float* __restrict__ bias,
    bf16* __restrict__ qo, bf16* __restrict__ ko, bf16* __restrict__ vTo,
    float* __restrict__ outF) {
  constexpr int MT = EPI ? 64 : 128;
  constexpr int MI = MT / 32;
  constexpr int BK = EPI ? 64 : 32;
  constexpr int NC = BK / 32;               // 32-col chunks per barrier
  constexpr int NIT = 1024 / BK;
  constexpr int ASZ = MT * BK;              // elems per A buffer
  constexpr int BSZ = 128 * BK;
  constexpr int RS = 136;
  constexpr int SME0 = 2 * ASZ + 2 * BSZ;
  constexpr int SME = EPI ? SME0 : (SME0 > 128 * RS ? SME0 : 128 * RS);
  __shared__ __attribute__((aligned(16))) bf16 smem[SME];

  int bx, by;
  {
    const int f = blockIdx.x;
    const int xcd = f & 7, idx = f >> 3;
    if constexpr (EPI == 0) { by = xcd * 4 + (idx & 3); bx = idx >> 2; }
    else                    { by = xcd * 8 + (idx & 7); bx = idx >> 3; }
  }

  const int t = threadIdx.x;
  const int L = t & 63;
  const int li = L & 15;
  const int qd = L >> 4;
  const int w = t >> 6;
  const int wm = (w >> 1) * (MT / 2);
  const int wn = (w & 1) * 64;
  const int bm0 = by * MT;
  const int bn0 = bx * 128;
  const int r_st = t >> 2;         // 0..63
  const int c_st = (t & 3) * 8;    // within a 32-col chunk

  const bf16* Ab = A + (size_t)bm0 * 1024;
  const bf16* Bb = Bw + (size_t)bn0 * 1024;

  auto issue = [&](int k0, int bi) {
    bf16* As_ = smem + bi * ASZ;
    bf16* Bs_ = smem + 2 * ASZ + bi * BSZ;
#pragma unroll
    for (int kc = 0; kc < NC; ++kc) {
      const int kk = k0 + kc * 32;
      // A chunk: MT rows x 32 cols
      gl_lds16(Ab + (size_t)r_st * 1024 + kk + c_st, As_ + kc * MT * 32 + t * 8);
      if constexpr (MT == 128)
        gl_lds16(Ab + (size_t)(r_st + 64) * 1024 + kk + c_st,
                 As_ + kc * MT * 32 + (t + 256) * 8);
      // B chunk: 128 rows x 32 cols
      gl_lds16(Bb + (size_t)r_st * 1024 + kk + c_st, Bs_ + kc * 4096 + t * 8);
      gl_lds16(Bb + (size_t)(r_st + 64) * 1024 + kk + c_st,
               Bs_ + kc * 4096 + (t + 256) * 8);
    }
  };

  f32x4 acc[MI][4] = {};
  issue(0, 0);
  for (int it = 0; it < NIT; ++it) {
    WAIT_VM0_BARRIER();
    if (it < NIT - 1) issue((it + 1) * BK, (it + 1) & 1);
    const bf16* Ac = smem + (it & 1) * ASZ;
    const bf16* Bc = smem + 2 * ASZ + (it & 1) * BSZ;
#pragma unroll
    for (int kc = 0; kc < NC; ++kc) {
      const bf16* Ak = Ac + kc * MT * 32;
      const bf16* Bk = Bc + kc * 4096;
      bf16x8 af[MI], bfr[4];
#pragma unroll
      for (int mi = 0; mi < MI; ++mi)
        af[mi] = *(const bf16x8*)(Ak + (wm + mi * 16 + li) * 32 + qd * 8);
#pragma unroll
      for (int ni = 0; ni < 4; ++ni)
        bfr[ni] = *(const bf16x8*)(Bk + (wn + ni * 16 + li) * 32 + qd * 8);
#pragma unroll
      for (int mi = 0; mi < MI; ++mi)
#pragma unroll
        for (int ni = 0; ni < 4; ++ni)
          acc[mi][ni] = __builtin_amdgcn_mfma_f32_16x16x32_bf16(
              af[mi], bfr[ni], acc[mi][ni], 0, 0, 0);
    }
  }

  if constexpr (EPI == 0) {
    const int which = bn0 >> 10;  // 0:q 1:k 2:v
    __syncthreads();
    bf16* Ct = smem;
    if (which == 2) {
#pragma unroll
      for (int mi = 0; mi < MI; ++mi) {
        const int m_l = wm + mi * 16 + qd * 4;
#pragma unroll
        for (int ni = 0; ni < 4; ++ni) {
          const int n_l = wn + ni * 16 + li;
          const float bi = bias[bn0 + n_l];
          bf16x4 pk;
#pragma unroll
          for (int r = 0; r < 4; ++r) pk[r] = (bf16)(acc[mi][ni][r] + bi);
          *(bf16x4*)(Ct + n_l * RS + m_l) = pk;
        }
      }
    } else {
      const float sc = (which == 0) ? LOG2E_OVER_8 : 1.0f;
#pragma unroll
      for (int mi = 0; mi < MI; ++mi) {
        const int m_l = wm + mi * 16 + qd * 4;
#pragma unroll
        for (int ni = 0; ni < 4; ++ni) {
          const int n_l = wn + ni * 16 + li;
          const float bi = bias[bn0 + n_l];
#pragma unroll
          for (int r = 0; r < 4; ++r)
            Ct[(m_l + r) * RS + n_l] = (bf16)((acc[mi][ni][r] + bi) * sc);
        }
      }
    }
    __syncthreads();
    const int jr = t >> 4;
    const int jc = t & 15;
#pragma unroll
    for (int pass = 0; pass < 8; ++pass) {
      const int row = pass * 16 + jr;
      bf16x8 vv = *(const bf16x8*)(Ct + row * RS + jc * 8);
      if (which == 2) {
        const int n_g = bn0 + row;
        const int hh = (n_g >> 6) & 15, dd = n_g & 63;
        const int bb = bm0 >> 11;
        const int s_b = (bm0 & 2047) + jc * 8;
        *(bf16x8*)(vTo + ((size_t)(bb * 16 + hh) * 64 + dd) * 2048 + s_b) = vv;
      } else {
        const int m_g = bm0 + row;
        const int bb = m_g >> 11, ss = m_g & 2047;
        const int n_g = bn0 + jc * 8;
        const int hh = (n_g >> 6) & 15, dd = n_g & 63;
        bf16* dst = (which == 0 ? qo : ko);
        *(bf16x8*)(dst + ((size_t)(bb * 16 + hh) * 2048 + ss) * 64 + dd) = vv;
      }
    }
  } else {
#pragma unroll
    for (int mi = 0; mi < MI; ++mi) {
      const int m_g = bm0 + wm + mi * 16 + qd * 4;
#pragma unroll
      for (int ni = 0; ni < 4; ++ni) {
        const int n_g = bn0 + wn + ni * 16 + li;
        const float bi = bias[n_g];
#pragma unroll
        for (int r = 0; r < 4; ++r)
          outF[(size_t)(m_g + r) * 1024 + n_g] = acc[mi][ni][r] + bi;
      }
    }
  }
}

// ---------------- flash attention: R20: R16 structure + MFMA row-sums ----------------
// R16 geometry (proven best 45.9us): grid 256, 512-thr blocks, 2 key-halves x
// 4 q-waves of 64q (two 32-q subtiles), K/V dbuf 128KB, XOR-swizzled staging,
// single vmcnt(0)+barrier per it2, K-frag hoist + V prefetch pinned with
// sched_barrier, no-max exp2 softmax, permlane32_swap P exchange, additive
// split-KV combine. NEW: softmax denominator via the MATRIX pipe -- one extra
// MFMA pair per kt with B = all-ones gives accS[q] = sum_k P[q,k] in exactly
// the acc C-layout (row = q). Deletes the 16-add serial lsl chain from every
// SM call, the lane-half shfl fold, and the 17-shuffle inv redistribution;
// normalize becomes per-register acc[r]/accS[r]. Numerator and denominator
// now both use bf16-rounded P (common-mode rounding cancels).
__global__ __launch_bounds__(512, 2) void attn_fwd(
    const bf16* __restrict__ Q, const bf16* __restrict__ K,
    const bf16* __restrict__ VT, bf16* __restrict__ AO) {
  // [half][ K dbuf 2x8192 | V dbuf 2x8192 ]  = 2 x 32768 bf16 = 128KB
  __shared__ __attribute__((aligned(16))) bf16 smem[65536];
  const int t = threadIdx.x;   // 0..511
  const int half = t >> 8;     // 0: keys [0,1024)  1: keys [1024,2048)
  const int tt = t & 255;      // index within half (staging)
  const int L = t & 63;
  const int m31 = L & 31;
  const int hi = (L >> 5) & 1;
  const int w = (t >> 6) & 3;  // wave within half: 0..3 -> q-subtile of 64

  const int lid = blockIdx.x;  // 0..255
  const int bh_ = ((lid & 7) << 2) + (lid >> 6);  // 4 bh per XCD
  const int qb = (lid >> 3) & 7;                  // 8 q-tiles of 256
  const int b = bh_ >> 4, h = bh_ & 15;
  const size_t bh = (size_t)(b * 16 + h);

  const bf16* Qp = Q + bh * 2048 * 64;
  const bf16* Kp = K + bh * 2048 * 64 + (size_t)half * 1024 * 64;
  const bf16* Vp = VT + bh * 64 * 2048 + half * 1024;  // [d][s], key-col offset
  const int q0 = qb * 256 + w * 64;   // wave's 64 q rows (same for both halves)

  // Q B-frags, per q-subtile: qf[qs][s] = Q[q0+qs*32+m31][s*16 + hi*8 .. +7]
  bf16x8 qf[2][4];
#pragma unroll
  for (int qs = 0; qs < 2; ++qs)
#pragma unroll
    for (int s = 0; s < 4; ++s)
      qf[qs][s] = *(const bf16x8*)(
          Qp + (size_t)(q0 + qs * 32 + m31) * 64 + s * 16 + hi * 8);

  // 4 accumulator chains [dt][qs] + 2 row-sum chains accS[qs] (same C-layout)
  f32x16 acc[2][2] = {};
  f32x16 accS[2] = {};

  // all-ones bf16 B-frag for the row-sum MFMA
  union FU { uint32_t u[4]; bf16x8 v; };
  FU onesf;
  onesf.u[0] = 0x3F803F80u; onesf.u[1] = 0x3F803F80u;
  onesf.u[2] = 0x3F803F80u; onesf.u[3] = 0x3F803F80u;

  bf16* Kbase = smem + half * 32768;
  bf16* Vbase = Kbase + 16384;

  // staging: phys 16B chunk p = row*8 + (cc ^ (row&7)); 256 thr/half, 2 rows each
  const int srow = tt >> 3;                // 0..31 (+32 on r=1)
  const int scc = (tt & 7) ^ (srow & 7);   // (srow+32)&7 == srow&7
  auto issue = [&](int it2, int bi) {
#pragma unroll
    for (int tile = 0; tile < 2; ++tile) {
      const int kt = it2 * 2 + tile;       // 0..15 within this half
      const bf16* Kt = Kp + (size_t)kt * 4096;
      const bf16* Vt = Vp + kt * 64;
      bf16* Kd = Kbase + bi * 8192 + tile * 4096;
      bf16* Vd = Vbase + bi * 8192 + tile * 4096;
#pragma unroll
      for (int r = 0; r < 2; ++r) {
        gl_lds16(Kt + (srow + 32 * r) * 64 + scc * 8, Kd + (tt + 256 * r) * 8);
        gl_lds16(Vt + (size_t)(srow + 32 * r) * 2048 + scc * 8, Vd + (tt + 256 * r) * 8);
      }
    }
  };

  const int rlow = m31 & 7;

  // SM: p = 2^s, pack to bf16 pairs, permlane exchange -> 2 A-frags (no lsl!)
  auto SM = [&](const f32x16& st, FU* afp) {
    uint32_t pk[8];
#pragma unroll
    for (int j = 0; j < 8; ++j) {
      float a = EXP2(st[2 * j]);
      float c = EXP2(st[2 * j + 1]);
      pk[j] = pack2(a, c);
    }
    pl32swap(pk[0], pk[2]);
    pl32swap(pk[1], pk[3]);
    pl32swap(pk[4], pk[6]);
    pl32swap(pk[5], pk[7]);
    afp[0].u[0] = pk[0]; afp[0].u[1] = pk[1];
    afp[0].u[2] = pk[2]; afp[0].u[3] = pk[3];
    afp[1].u[0] = pk[4]; afp[1].u[1] = pk[5];
    afp[1].u[2] = pk[6]; afp[1].u[3] = pk[7];
  };

  issue(0, 0);
  for (int it2 = 0; it2 < 8; ++it2) {      // 8 iters x 128 keys = this half's 1024
    WAIT_VM0_BARRIER();
    if (it2 < 7) issue(it2 + 1, (it2 + 1) & 1);
    const bf16* Kc0 = Kbase + (it2 & 1) * 8192;
    const bf16* Vc0 = Vbase + (it2 & 1) * 8192;

    // ---- hoist ALL K-frags of this 128-key tile into registers (16 b128) ----
    bf16x8 kfa[4][4];
#pragma unroll
    for (int kt = 0; kt < 4; ++kt)
#pragma unroll
      for (int s = 0; s < 4; ++s)
        kfa[kt][s] = *(const bf16x8*)(
            Kc0 + (kt >> 1) * 4096 +
            (((kt & 1) * 32 + m31) * 8 + ((2 * s + hi) ^ rlow)) * 8);
    __builtin_amdgcn_sched_barrier(0);   // pin the burst above the compute

#pragma unroll
    for (int kt = 0; kt < 4; ++kt) {
      // QK^T from registers: 2 independent 4-MFMA chains (qs)
      f32x16 st2[2];
      __builtin_amdgcn_s_setprio(1);
#pragma unroll
      for (int qs = 0; qs < 2; ++qs) {
        f32x16 z = {};
#pragma unroll
        for (int s = 0; s < 4; ++s)
          z = __builtin_amdgcn_mfma_f32_32x32x16_bf16(kfa[kt][s], qf[qs][s], z,
                                                      0, 0, 0);
        st2[qs] = z;
      }
      __builtin_amdgcn_s_setprio(0);

      // prefetch V-frags for this kt; softmax below covers their latency
      bf16x8 vfa[2][2];
#pragma unroll
      for (int dt = 0; dt < 2; ++dt)
#pragma unroll
        for (int u = 0; u < 2; ++u)
          vfa[dt][u] = *(const bf16x8*)(
              Vc0 + (kt >> 1) * 4096 +
              ((dt * 32 + m31) * 8 + (((kt & 1) * 4 + u * 2 + hi) ^ rlow)) * 8);
      __builtin_amdgcn_sched_barrier(0); // pin the V burst above the softmax

      FU A[2][2];
      SM(st2[0], A[0]);
      SM(st2[1], A[1]);

      // O += P @ V  and  accS += P @ ones  (row-sums on the matrix pipe)
      __builtin_amdgcn_s_setprio(1);
#pragma unroll
      for (int qs = 0; qs < 2; ++qs)
#pragma unroll
        for (int u = 0; u < 2; ++u)
          accS[qs] = __builtin_amdgcn_mfma_f32_32x32x16_bf16(
              A[qs][u].v, onesf.v, accS[qs], 0, 0, 0);
#pragma unroll
      for (int dt = 0; dt < 2; ++dt)
#pragma unroll
        for (int u = 0; u < 2; ++u)
#pragma unroll
          for (int qs = 0; qs < 2; ++qs)
            acc[dt][qs] = __builtin_amdgcn_mfma_f32_32x32x16_bf16(
                A[qs][u].v, vfa[dt][u], acc[dt][qs], 0, 0, 0);
      __builtin_amdgcn_s_setprio(0);
    }
  }

  // ---- split-KV combine (no-max softmax => partials ADD) ----
  // K/V LDS dead; reuse as exchange: 256 slots x 97 floats (64 acc + 32 accS),
  // stride 97 = 1 mod 32 -> clean bank spread. 256*97*4B = 99KB <= 128KB.
  __syncthreads();
  float* xch = (float*)smem;
  const int slot = w * 64 + L;
  float* rec = xch + (size_t)slot * 97;
  if (half == 1) {
#pragma unroll
    for (int dt = 0; dt < 2; ++dt)
#pragma unroll
      for (int qs = 0; qs < 2; ++qs)
#pragma unroll
        for (int r = 0; r < 16; ++r)
          rec[dt * 32 + qs * 16 + r] = acc[dt][qs][r];
#pragma unroll
    for (int qs = 0; qs < 2; ++qs)
#pragma unroll
      for (int r = 0; r < 16; ++r)
        rec[64 + qs * 16 + r] = accS[qs][r];
  }
  __syncthreads();
  if (half == 0) {
#pragma unroll
    for (int dt = 0; dt < 2; ++dt)
#pragma unroll
      for (int qs = 0; qs < 2; ++qs)
#pragma unroll
        for (int r = 0; r < 16; ++r)
          acc[dt][qs][r] += rec[dt * 32 + qs * 16 + r];
#pragma unroll
    for (int qs = 0; qs < 2; ++qs)
#pragma unroll
      for (int r = 0; r < 16; ++r)
        accS[qs][r] += rec[64 + qs * 16 + r];

    // normalize + store: accS is in the SAME C-layout as acc -> no shuffles
#pragma unroll
    for (int qs = 0; qs < 2; ++qs)
#pragma unroll
      for (int r = 0; r < 16; ++r) {
        const int qrow = (r & 3) + 8 * (r >> 2) + 4 * hi;
        const float invq = 1.f / accS[qs][r];
        const size_t base =
            ((size_t)b * 2048 + q0 + qs * 32 + qrow) * 1024 + h * 64 + m31;
        AO[base] = (bf16)(acc[0][qs][r] * invq);
        AO[base + 32] = (bf16)(acc[1][qs][r] * invq);
      }
  }
}

// ---------------- launch ----------------
extern "C" void kernel_launch(void* const* d_in, const int* in_sizes, int n_in,
                              void* d_out, int out_size, void* d_ws, size_t ws_size,
                              hipStream_t stream) {
  const float* x = (const float*)d_in[0];
  const float* qkvw = (const float*)d_in[1];
  const float* qkvb = (const float*)d_in[2];
  const float* outw = (const float*)d_in[3];
  const float* outb = (const float*)d_in[4];
  float* out = (float*)d_out;

  bf16* xb = (bf16*)d_ws;                     // 4096*1024
  bf16* wq = xb + (size_t)N_X;                // 3072*1024
  bf16* wo = wq + (size_t)N_WQ;               // 1024*1024
  bf16* q = wo + (size_t)N_WO;                // 32*2048*64
  bf16* kk = q + (size_t)2 * 16 * 2048 * 64;
  bf16* vT = kk + (size_t)2 * 16 * 2048 * 64;
  bf16* attn = xb;                            // alias (xb dead after GEMM1)

  cvt3_kernel<<<4096, 256, 0, stream>>>(x, qkvw, outw, xb);

  gemm_bt<0><<<768, 256, 0, stream>>>(xb, wq, qkvb, q, kk, vT, nullptr);
  attn_fwd<<<256, 512, 0, stream>>>(q, kk, vT, attn);
  gemm_bt<1><<<512, 256, 0, stream>>>(attn, wo, outb, nullptr, nullptr, nullptr, out);
}

// Round 12
// 176.448 us; speedup vs baseline: 1.0006x; 1.0006x over previous
//
#include <hip/hip_runtime.h>
#include <stdint.h>

typedef __bf16 bf16;
typedef __attribute__((ext_vector_type(2))) __bf16 bf16x2;
typedef __attribute__((ext_vector_type(4))) __bf16 bf16x4;
typedef __attribute__((ext_vector_type(8))) __bf16 bf16x8;
typedef __attribute__((ext_vector_type(4))) float f32x4;
typedef __attribute__((ext_vector_type(16))) float f32x16;

#define LOG2E_OVER_8 0.18033688011112042f  // log2(e)/sqrt(64), folded into q

#if __has_builtin(__builtin_amdgcn_exp2f)
#define EXP2(x) __builtin_amdgcn_exp2f(x)   // raw v_exp_f32: D = 2^S0
#else
#define EXP2(x) exp2f(x)
#endif

// async global->LDS, 16B/lane; LDS dest = wave-uniform base + lane*16
__device__ __forceinline__ void gl_lds16(const bf16* g, bf16* l) {
  __builtin_amdgcn_global_load_lds(
      (const __attribute__((address_space(1))) void*)g,
      (__attribute__((address_space(3))) void*)l, 16, 0, 0);
}
// wait own loads, then sync -> everyone's loads are in LDS; DMA issued after
// this line stays in flight through the whole compute phase.
#define WAIT_VM0_BARRIER() asm volatile("s_waitcnt vmcnt(0)\n\ts_barrier" ::: "memory")

__device__ __forceinline__ uint32_t pack2(float a, float b) {
  union { bf16x2 v; uint32_t u; } z;
  z.v[0] = (bf16)a; z.v[1] = (bf16)b;
  return z.u;
}

// v_permlane32_swap_b32 a, b : a.hi31 <-> b.lo31
//   after: a = {a.lo, b.lo}, b = {a.hi, b.hi}
__device__ __forceinline__ void pl32swap(uint32_t& a, uint32_t& b) {
  asm("v_permlane32_swap_b32 %0, %1" : "+v"(a), "+v"(b));
}

// ---------------- fused fp32 -> bf16 convert (x, qkv_w, out_w) ----------------
#define N_X  (4096 * 1024)
#define N_WQ (3072 * 1024)
#define N_WO (1024 * 1024)
__global__ __launch_bounds__(256) void cvt3_kernel(const float* __restrict__ x,
                                                   const float* __restrict__ wq,
                                                   const float* __restrict__ wo,
                                                   bf16* __restrict__ d) {
  int i = (blockIdx.x * 256 + threadIdx.x) * 8;
  const float* s;
  if (i < N_X) s = x + i;
  else if (i < N_X + N_WQ) s = wq + (i - N_X);
  else s = wo + (i - N_X - N_WQ);
  float4 a = *(const float4*)s;
  float4 b = *(const float4*)(s + 4);
  bf16x8 o;
  o[0] = (bf16)a.x; o[1] = (bf16)a.y; o[2] = (bf16)a.z; o[3] = (bf16)a.w;
  o[4] = (bf16)b.x; o[5] = (bf16)b.y; o[6] = (bf16)b.z; o[7] = (bf16)b.w;
  *(bf16x8*)(d + i) = o;
}

// ---------------- NT GEMM (gemm1): 64x128 tile, BK=64, fp32 out + bias ----------------
template <int EPI>
__global__ __launch_bounds__(256, 3) void gemm_bt(
    const bf16* __restrict__ A, const bf16* __restrict__ Bw,
    const float* __restrict__ bias,
    bf16* __restrict__ qo, bf16* __restrict__ ko, bf16* __restrict__ vTo,
    float* __restrict__ outF) {
  constexpr int MT = EPI ? 64 : 128;
  constexpr int MI = MT / 32;
  constexpr int BK = EPI ? 64 : 32;
  constexpr int NC = BK / 32;               // 32-col chunks per barrier
  constexpr int NIT = 1024 / BK;
  constexpr int ASZ = MT * BK;              // elems per A buffer
  constexpr int BSZ = 128 * BK;
  constexpr int RS = 136;
  constexpr int SME0 = 2 * ASZ + 2 * BSZ;
  constexpr int SME = EPI ? SME0 : (SME0 > 128 * RS ? SME0 : 128 * RS);
  __shared__ __attribute__((aligned(16))) bf16 smem[SME];

  int bx, by;
  {
    const int f = blockIdx.x;
    const int xcd = f & 7, idx = f >> 3;
    if constexpr (EPI == 0) { by = xcd * 4 + (idx & 3); bx = idx >> 2; }
    else                    { by = xcd * 8 + (idx & 7); bx = idx >> 3; }
  }

  const int t = threadIdx.x;
  const int L = t & 63;
  const int li = L & 15;
  const int qd = L >> 4;
  const int w = t >> 6;
  const int wm = (w >> 1) * (MT / 2);
  const int wn = (w & 1) * 64;
  const int bm0 = by * MT;
  const int bn0 = bx * 128;
  const int r_st = t >> 2;         // 0..63
  const int c_st = (t & 3) * 8;    // within a 32-col chunk

  const bf16* Ab = A + (size_t)bm0 * 1024;
  const bf16* Bb = Bw + (size_t)bn0 * 1024;

  auto issue = [&](int k0, int bi) {
    bf16* As_ = smem + bi * ASZ;
    bf16* Bs_ = smem + 2 * ASZ + bi * BSZ;
#pragma unroll
    for (int kc = 0; kc < NC; ++kc) {
      const int kk = k0 + kc * 32;
      gl_lds16(Ab + (size_t)r_st * 1024 + kk + c_st, As_ + kc * MT * 32 + t * 8);
      if constexpr (MT == 128)
        gl_lds16(Ab + (size_t)(r_st + 64) * 1024 + kk + c_st,
                 As_ + kc * MT * 32 + (t + 256) * 8);
      gl_lds16(Bb + (size_t)r_st * 1024 + kk + c_st, Bs_ + kc * 4096 + t * 8);
      gl_lds16(Bb + (size_t)(r_st + 64) * 1024 + kk + c_st,
               Bs_ + kc * 4096 + (t + 256) * 8);
    }
  };

  f32x4 acc[MI][4] = {};
  issue(0, 0);
  for (int it = 0; it < NIT; ++it) {
    WAIT_VM0_BARRIER();
    if (it < NIT - 1) issue((it + 1) * BK, (it + 1) & 1);
    const bf16* Ac = smem + (it & 1) * ASZ;
    const bf16* Bc = smem + 2 * ASZ + (it & 1) * BSZ;
#pragma unroll
    for (int kc = 0; kc < NC; ++kc) {
      const bf16* Ak = Ac + kc * MT * 32;
      const bf16* Bk = Bc + kc * 4096;
      bf16x8 af[MI], bfr[4];
#pragma unroll
      for (int mi = 0; mi < MI; ++mi)
        af[mi] = *(const bf16x8*)(Ak + (wm + mi * 16 + li) * 32 + qd * 8);
#pragma unroll
      for (int ni = 0; ni < 4; ++ni)
        bfr[ni] = *(const bf16x8*)(Bk + (wn + ni * 16 + li) * 32 + qd * 8);
#pragma unroll
      for (int mi = 0; mi < MI; ++mi)
#pragma unroll
        for (int ni = 0; ni < 4; ++ni)
          acc[mi][ni] = __builtin_amdgcn_mfma_f32_16x16x32_bf16(
              af[mi], bfr[ni], acc[mi][ni], 0, 0, 0);
    }
  }

  if constexpr (EPI == 0) {
    // (unused in this configuration; kept for reference)
  } else {
#pragma unroll
    for (int mi = 0; mi < MI; ++mi) {
      const int m_g = bm0 + wm + mi * 16 + qd * 4;
#pragma unroll
      for (int ni = 0; ni < 4; ++ni) {
        const int n_g = bn0 + wn + ni * 16 + li;
        const float bi = bias[n_g];
#pragma unroll
        for (int r = 0; r < 4; ++r)
          outF[(size_t)(m_g + r) * 1024 + n_g] = acc[mi][ni][r] + bi;
      }
    }
  }
}

// ---------------- gemm0: 256x256 tile (R21) ----------------
// QKV projection 4096x3072x1024. At 128-tiles the operand re-read traffic is
// A x24 + B x32 = 384MB through L2/L3 (~820cy/K-step/CU vs ~240cy MFMA) ->
// fetch-bound, which is why pipelining tweaks (R12) were null. 256x256 halves
// traffic to 192MB and doubles MFMA per barrier window (32/wave/K-step).
// 512 thr / 8 waves (wave owns 128x64, acc[8][4] ~206 VGPR under (512,2) cap);
// same proven single-barrier prefetch K-loop + [row][32] LDS chunk layout
// (64KB dbuf). Grid 16x12=192, XCD-bijective (192%8==0). Epilogue: four
// 64-row (q/k) / 64-col (v) slabs through the dead staging LDS, uniform
// barriers; global store patterns identical to the proven 128^2 epilogue.
__global__ __launch_bounds__(512, 2) void gemm256(
    const bf16* __restrict__ A, const bf16* __restrict__ Bw,
    const float* __restrict__ bias,
    bf16* __restrict__ qo, bf16* __restrict__ ko, bf16* __restrict__ vTo) {
  constexpr int BK = 32;
  constexpr int NIT = 32;
  constexpr int ASZ = 256 * BK;             // 8192 elems = 16KB
  constexpr int BSZ = 256 * BK;
  constexpr int RS2 = 264;                  // slab row stride (16B-aligned)
  __shared__ __attribute__((aligned(16))) bf16 smem[2 * ASZ + 2 * BSZ];  // 64KB

  const int f = blockIdx.x;                 // 0..191
  const int xcd = f & 7, idx = f >> 3;      // idx 0..23
  const int by = xcd * 2 + (idx & 1);       // 0..15  (M-tiles)
  const int bx = idx >> 1;                  // 0..11  (N-tiles)

  const int t = threadIdx.x;                // 0..511
  const int L = t & 63;
  const int li = L & 15;
  const int qd = L >> 4;
  const int w = t >> 6;                     // 0..7
  const int wm = (w >> 2) * 128;            // 0,128
  const int wn = (w & 3) * 64;              // 0,64,128,192
  const int bm0 = by * 256;
  const int bn0 = bx * 256;
  const int r_st = t >> 2;                  // 0..127
  const int c_st = (t & 3) * 8;

  const bf16* Ab = A + (size_t)bm0 * 1024;
  const bf16* Bb = Bw + (size_t)bn0 * 1024;

  auto issue = [&](int kk, int bi) {
    bf16* As_ = smem + bi * ASZ;
    bf16* Bs_ = smem + 2 * ASZ + bi * BSZ;
    gl_lds16(Ab + (size_t)r_st * 1024 + kk + c_st, As_ + t * 8);
    gl_lds16(Ab + (size_t)(r_st + 128) * 1024 + kk + c_st, As_ + (t + 512) * 8);
    gl_lds16(Bb + (size_t)r_st * 1024 + kk + c_st, Bs_ + t * 8);
    gl_lds16(Bb + (size_t)(r_st + 128) * 1024 + kk + c_st, Bs_ + (t + 512) * 8);
  };

  f32x4 acc[8][4] = {};
  issue(0, 0);
  for (int it = 0; it < NIT; ++it) {
    WAIT_VM0_BARRIER();
    if (it < NIT - 1) issue((it + 1) * BK, (it + 1) & 1);
    const bf16* Ak = smem + (it & 1) * ASZ;
    const bf16* Bk = smem + 2 * ASZ + (it & 1) * BSZ;
    bf16x8 af[8], bfr[4];
#pragma unroll
    for (int mi = 0; mi < 8; ++mi)
      af[mi] = *(const bf16x8*)(Ak + (wm + mi * 16 + li) * 32 + qd * 8);
#pragma unroll
    for (int ni = 0; ni < 4; ++ni)
      bfr[ni] = *(const bf16x8*)(Bk + (wn + ni * 16 + li) * 32 + qd * 8);
#pragma unroll
    for (int mi = 0; mi < 8; ++mi)
#pragma unroll
      for (int ni = 0; ni < 4; ++ni)
        acc[mi][ni] = __builtin_amdgcn_mfma_f32_16x16x32_bf16(
            af[mi], bfr[ni], acc[mi][ni], 0, 0, 0);
  }

  const int which = bn0 >> 10;  // 0:q 1:k 2:v  (256 | 1024 -> tile is pure)
  bf16* Ct = smem;
  if (which != 2) {
    const float sc = (which == 0) ? LOG2E_OVER_8 : 1.0f;
    bf16* dst = (which == 0) ? qo : ko;
#pragma unroll
    for (int slab = 0; slab < 4; ++slab) {   // 64 output rows per slab
      __syncthreads();                       // Ct free (staging dead / prev slab read)
      if ((wm >> 7) == (slab >> 1)) {
        const int mib = (slab & 1) * 4;
#pragma unroll
        for (int mi2 = 0; mi2 < 4; ++mi2) {
          const int mi = mib + mi2;
          const int lr = mi2 * 16 + qd * 4;  // local row base in slab
#pragma unroll
          for (int ni = 0; ni < 4; ++ni) {
            const int n_l = wn + ni * 16 + li;
            const float bi = bias[bn0 + n_l];
#pragma unroll
            for (int r = 0; r < 4; ++r)
              Ct[(lr + r) * RS2 + n_l] = (bf16)((acc[mi][ni][r] + bi) * sc);
          }
        }
      }
      __syncthreads();
      const int row = t >> 3;                // 0..63
      const int m_g = bm0 + slab * 64 + row;
      const int bb = m_g >> 11, ss = m_g & 2047;
#pragma unroll
      for (int p = 0; p < 4; ++p) {
        const int c8 = (t & 7) + p * 8;      // 0..31 (16B col chunks)
        bf16x8 vv = *(const bf16x8*)(Ct + row * RS2 + c8 * 8);
        const int n_g = bn0 + c8 * 8;
        const int hh = (n_g >> 6) & 15, dd = n_g & 63;
        *(bf16x8*)(dst + ((size_t)(bb * 16 + hh) * 2048 + ss) * 64 + dd) = vv;
      }
    }
  } else {
#pragma unroll
    for (int slab = 0; slab < 4; ++slab) {   // 64 output cols (one head) per slab
      __syncthreads();
      if ((w & 3) == slab) {                 // wave's wn range == this slab
#pragma unroll
        for (int ni = 0; ni < 4; ++ni) {
          const int nl = ni * 16 + li;       // 0..63 within slab
          const float bi = bias[bn0 + slab * 64 + nl];
#pragma unroll
          for (int mi = 0; mi < 8; ++mi) {
            const int m_l = wm + mi * 16 + qd * 4;
            bf16x4 pk;
#pragma unroll
            for (int r = 0; r < 4; ++r) pk[r] = (bf16)(acc[mi][ni][r] + bi);
            *(bf16x4*)(Ct + nl * RS2 + m_l) = pk;  // transposed: [d][s]
          }
        }
      }
      __syncthreads();
      const int row = t >> 3;                // d-row within slab, 0..63
      const int n_g = bn0 + slab * 64 + row;
      const int hh = (n_g >> 6) & 15, dd = n_g & 63;
      const int bb = bm0 >> 11;
#pragma unroll
      for (int p = 0; p < 4; ++p) {
        const int c8 = (t & 7) + p * 8;      // s chunk 0..31
        bf16x8 vv = *(const bf16x8*)(Ct + row * RS2 + c8 * 8);
        const int s_b = (bm0 & 2047) + c8 * 8;
        *(bf16x8*)(vTo + ((size_t)(bb * 16 + hh) * 64 + dd) * 2048 + s_b) = vv;
      }
    }
  }
}

// ---------------- flash attention: R20 (kept): R16 structure + MFMA row-sums ----------------
__global__ __launch_bounds__(512, 2) void attn_fwd(
    const bf16* __restrict__ Q, const bf16* __restrict__ K,
    const bf16* __restrict__ VT, bf16* __restrict__ AO) {
  // [half][ K dbuf 2x8192 | V dbuf 2x8192 ]  = 2 x 32768 bf16 = 128KB
  __shared__ __attribute__((aligned(16))) bf16 smem[65536];
  const int t = threadIdx.x;   // 0..511
  const int half = t >> 8;     // 0: keys [0,1024)  1: keys [1024,2048)
  const int tt = t & 255;      // index within half (staging)
  const int L = t & 63;
  const int m31 = L & 31;
  const int hi = (L >> 5) & 1;
  const int w = (t >> 6) & 3;  // wave within half: 0..3 -> q-subtile of 64

  const int lid = blockIdx.x;  // 0..255
  const int bh_ = ((lid & 7) << 2) + (lid >> 6);  // 4 bh per XCD
  const int qb = (lid >> 3) & 7;                  // 8 q-tiles of 256
  const int b = bh_ >> 4, h = bh_ & 15;
  const size_t bh = (size_t)(b * 16 + h);

  const bf16* Qp = Q + bh * 2048 * 64;
  const bf16* Kp = K + bh * 2048 * 64 + (size_t)half * 1024 * 64;
  const bf16* Vp = VT + bh * 64 * 2048 + half * 1024;  // [d][s], key-col offset
  const int q0 = qb * 256 + w * 64;   // wave's 64 q rows (same for both halves)

  // Q B-frags, per q-subtile: qf[qs][s] = Q[q0+qs*32+m31][s*16 + hi*8 .. +7]
  bf16x8 qf[2][4];
#pragma unroll
  for (int qs = 0; qs < 2; ++qs)
#pragma unroll
    for (int s = 0; s < 4; ++s)
      qf[qs][s] = *(const bf16x8*)(
          Qp + (size_t)(q0 + qs * 32 + m31) * 64 + s * 16 + hi * 8);

  // 4 accumulator chains [dt][qs] + 2 row-sum chains accS[qs] (same C-layout)
  f32x16 acc[2][2] = {};
  f32x16 accS[2] = {};

  // all-ones bf16 B-frag for the row-sum MFMA
  union FU { uint32_t u[4]; bf16x8 v; };
  FU onesf;
  onesf.u[0] = 0x3F803F80u; onesf.u[1] = 0x3F803F80u;
  onesf.u[2] = 0x3F803F80u; onesf.u[3] = 0x3F803F80u;

  bf16* Kbase = smem + half * 32768;
  bf16* Vbase = Kbase + 16384;

  // staging: phys 16B chunk p = row*8 + (cc ^ (row&7)); 256 thr/half, 2 rows each
  const int srow = tt >> 3;                // 0..31 (+32 on r=1)
  const int scc = (tt & 7) ^ (srow & 7);   // (srow+32)&7 == srow&7
  auto issue = [&](int it2, int bi) {
#pragma unroll
    for (int tile = 0; tile < 2; ++tile) {
      const int kt = it2 * 2 + tile;       // 0..15 within this half
      const bf16* Kt = Kp + (size_t)kt * 4096;
      const bf16* Vt = Vp + kt * 64;
      bf16* Kd = Kbase + bi * 8192 + tile * 4096;
      bf16* Vd = Vbase + bi * 8192 + tile * 4096;
#pragma unroll
      for (int r = 0; r < 2; ++r) {
        gl_lds16(Kt + (srow + 32 * r) * 64 + scc * 8, Kd + (tt + 256 * r) * 8);
        gl_lds16(Vt + (size_t)(srow + 32 * r) * 2048 + scc * 8, Vd + (tt + 256 * r) * 8);
      }
    }
  };

  const int rlow = m31 & 7;

  // SM: p = 2^s, pack to bf16 pairs, permlane exchange -> 2 A-frags (no lsl)
  auto SM = [&](const f32x16& st, FU* afp) {
    uint32_t pk[8];
#pragma unroll
    for (int j = 0; j < 8; ++j) {
      float a = EXP2(st[2 * j]);
      float c = EXP2(st[2 * j + 1]);
      pk[j] = pack2(a, c);
    }
    pl32swap(pk[0], pk[2]);
    pl32swap(pk[1], pk[3]);
    pl32swap(pk[4], pk[6]);
    pl32swap(pk[5], pk[7]);
    afp[0].u[0] = pk[0]; afp[0].u[1] = pk[1];
    afp[0].u[2] = pk[2]; afp[0].u[3] = pk[3];
    afp[1].u[0] = pk[4]; afp[1].u[1] = pk[5];
    afp[1].u[2] = pk[6]; afp[1].u[3] = pk[7];
  };

  issue(0, 0);
  for (int it2 = 0; it2 < 8; ++it2) {      // 8 iters x 128 keys = this half's 1024
    WAIT_VM0_BARRIER();
    if (it2 < 7) issue(it2 + 1, (it2 + 1) & 1);
    const bf16* Kc0 = Kbase + (it2 & 1) * 8192;
    const bf16* Vc0 = Vbase + (it2 & 1) * 8192;

    // ---- hoist ALL K-frags of this 128-key tile into registers (16 b128) ----
    bf16x8 kfa[4][4];
#pragma unroll
    for (int kt = 0; kt < 4; ++kt)
#pragma unroll
      for (int s = 0; s < 4; ++s)
        kfa[kt][s] = *(const bf16x8*)(
            Kc0 + (kt >> 1) * 4096 +
            (((kt & 1) * 32 + m31) * 8 + ((2 * s + hi) ^ rlow)) * 8);
    __builtin_amdgcn_sched_barrier(0);   // pin the burst above the compute

#pragma unroll
    for (int kt = 0; kt < 4; ++kt) {
      // QK^T from registers: 2 independent 4-MFMA chains (qs)
      f32x16 st2[2];
      __builtin_amdgcn_s_setprio(1);
#pragma unroll
      for (int qs = 0; qs < 2; ++qs) {
        f32x16 z = {};
#pragma unroll
        for (int s = 0; s < 4; ++s)
          z = __builtin_amdgcn_mfma_f32_32x32x16_bf16(kfa[kt][s], qf[qs][s], z,
                                                      0, 0, 0);
        st2[qs] = z;
      }
      __builtin_amdgcn_s_setprio(0);

      // prefetch V-frags for this kt; softmax below covers their latency
      bf16x8 vfa[2][2];
#pragma unroll
      for (int dt = 0; dt < 2; ++dt)
#pragma unroll
        for (int u = 0; u < 2; ++u)
          vfa[dt][u] = *(const bf16x8*)(
              Vc0 + (kt >> 1) * 4096 +
              ((dt * 32 + m31) * 8 + (((kt & 1) * 4 + u * 2 + hi) ^ rlow)) * 8);
      __builtin_amdgcn_sched_barrier(0); // pin the V burst above the softmax

      FU A[2][2];
      SM(st2[0], A[0]);
      SM(st2[1], A[1]);

      // O += P @ V  and  accS += P @ ones  (row-sums on the matrix pipe)
      __builtin_amdgcn_s_setprio(1);
#pragma unroll
      for (int qs = 0; qs < 2; ++qs)
#pragma unroll
        for (int u = 0; u < 2; ++u)
          accS[qs] = __builtin_amdgcn_mfma_f32_32x32x16_bf16(
              A[qs][u].v, onesf.v, accS[qs], 0, 0, 0);
#pragma unroll
      for (int dt = 0; dt < 2; ++dt)
#pragma unroll
        for (int u = 0; u < 2; ++u)
#pragma unroll
          for (int qs = 0; qs < 2; ++qs)
            acc[dt][qs] = __builtin_amdgcn_mfma_f32_32x32x16_bf16(
                A[qs][u].v, vfa[dt][u], acc[dt][qs], 0, 0, 0);
      __builtin_amdgcn_s_setprio(0);
    }
  }

  // ---- split-KV combine (no-max softmax => partials ADD) ----
  // K/V LDS dead; reuse as exchange: 256 slots x 97 floats (64 acc + 32 accS),
  // stride 97 = 1 mod 32 -> clean bank spread. 256*97*4B = 99KB <= 128KB.
  __syncthreads();
  float* xch = (float*)smem;
  const int slot = w * 64 + L;
  float* rec = xch + (size_t)slot * 97;
  if (half == 1) {
#pragma unroll
    for (int dt = 0; dt < 2; ++dt)
#pragma unroll
      for (int qs = 0; qs < 2; ++qs)
#pragma unroll
        for (int r = 0; r < 16; ++r)
          rec[dt * 32 + qs * 16 + r] = acc[dt][qs][r];
#pragma unroll
    for (int qs = 0; qs < 2; ++qs)
#pragma unroll
      for (int r = 0; r < 16; ++r)
        rec[64 + qs * 16 + r] = accS[qs][r];
  }
  __syncthreads();
  if (half == 0) {
#pragma unroll
    for (int dt = 0; dt < 2; ++dt)
#pragma unroll
      for (int qs = 0; qs < 2; ++qs)
#pragma unroll
        for (int r = 0; r < 16; ++r)
          acc[dt][qs][r] += rec[dt * 32 + qs * 16 + r];
#pragma unroll
    for (int qs = 0; qs < 2; ++qs)
#pragma unroll
      for (int r = 0; r < 16; ++r)
        accS[qs][r] += rec[64 + qs * 16 + r];

    // normalize + store: accS is in the SAME C-layout as acc -> no shuffles
#pragma unroll
    for (int qs = 0; qs < 2; ++qs)
#pragma unroll
      for (int r = 0; r < 16; ++r) {
        const int qrow = (r & 3) + 8 * (r >> 2) + 4 * hi;
        const float invq = 1.f / accS[qs][r];
        const size_t base =
            ((size_t)b * 2048 + q0 + qs * 32 + qrow) * 1024 + h * 64 + m31;
        AO[base] = (bf16)(acc[0][qs][r] * invq);
        AO[base + 32] = (bf16)(acc[1][qs][r] * invq);
      }
  }
}

// ---------------- launch ----------------
extern "C" void kernel_launch(void* const* d_in, const int* in_sizes, int n_in,
                              void* d_out, int out_size, void* d_ws, size_t ws_size,
                              hipStream_t stream) {
  const float* x = (const float*)d_in[0];
  const float* qkvw = (const float*)d_in[1];
  const float* qkvb = (const float*)d_in[2];
  const float* outw = (const float*)d_in[3];
  const float* outb = (const float*)d_in[4];
  float* out = (float*)d_out;

  bf16* xb = (bf16*)d_ws;                     // 4096*1024
  bf16* wq = xb + (size_t)N_X;                // 3072*1024
  bf16* wo = wq + (size_t)N_WQ;               // 1024*1024
  bf16* q = wo + (size_t)N_WO;                // 32*2048*64
  bf16* kk = q + (size_t)2 * 16 * 2048 * 64;
  bf16* vT = kk + (size_t)2 * 16 * 2048 * 64;
  bf16* attn = xb;                            // alias (xb dead after GEMM1)

  cvt3_kernel<<<4096, 256, 0, stream>>>(x, qkvw, outw, xb);

  gemm256<<<192, 512, 0, stream>>>(xb, wq, qkvb, q, kk, vT);
  attn_fwd<<<256, 512, 0, stream>>>(q, kk, vT, attn);
  gemm_bt<1><<<512, 256, 0, stream>>>(attn, wo, outb, nullptr, nullptr, nullptr, out);
}